// Round 4
// baseline (97.940 us; speedup 1.0000x reference)
//
#include <hip/hip_runtime.h>
#include <math.h>

#define S_LEN 2048
#define D_MODEL 512
#define NIMU 13
#define NCOL 117                 // 13*9
#define CPAD 128                 // padded col stride
#define NKC 8                    // k-split chunks
// Pt[kc][c][s] = Pt[(kc*CPAD + c)*S_LEN + s]
#define KCSTRIDE ((size_t)CPAD * S_LEN)

static __device__ __forceinline__ float softplus_f(float x) {
    return (x > 20.f) ? x : log1pf(expf(x));
}

// osc transform: params -> per-step rotation z and state at dt0
static __device__ __forceinline__ void osc_init(float pk, float pd, float amp, float phi, float dtf,
                                                float& re, float& im, float& zr, float& zi)
{
    const float LOG2E = 1.4426950408889634f;
    const float INV2PI = 0.15915494309189535f;
    float d = sqrtf(pd * pd + 1e-5f);
    float kk = d * d * 0.25f + softplus_f(pk);
    float om = 0.5f * sqrtf(fmaxf(4.f * kk - d * d, 0.f));
    float y = -0.5f * d * LOG2E;       // log2 of decay per step
    float f = om * INV2PI;             // revolutions per step
    float ph = phi * INV2PI;
    float ez = __builtin_amdgcn_exp2f(y);
    zr = ez * __builtin_amdgcn_cosf(f);
    zi = ez * __builtin_amdgcn_sinf(f);
    float er = amp * __builtin_amdgcn_exp2f(dtf * y);
    float r = fmaf(dtf, f, ph); r -= floorf(r);
    re = er * __builtin_amdgcn_cosf(r);
    im = er * __builtin_amdgcn_sinf(r);
}

// ---------------- kernel 1: LN stats + W pad + out zero ----------------
__global__ __launch_bounds__(256) void stats_kernel(const float* __restrict__ H,
                                                    float2* __restrict__ stats,
                                                    const float* __restrict__ W,
                                                    float* __restrict__ Wp,
                                                    float* __restrict__ out) {
    if (blockIdx.x < 104) out[blockIdx.x * 256 + threadIdx.x] = 0.f;   // 104*256 = 26624 = 13*2048
    if (threadIdx.x < CPAD) {
        int c = threadIdx.x;
        Wp[blockIdx.x * CPAD + c] = (c < NCOL) ? W[blockIdx.x * NCOL + c] : 0.f;
    }
    int wave = threadIdx.x >> 6;
    int lane = threadIdx.x & 63;
    int row = blockIdx.x * 4 + wave;
    const float* hr = H + row * D_MODEL;
    float4 a = *(const float4*)&hr[lane * 4];
    float4 b = *(const float4*)&hr[256 + lane * 4];
    float sum = a.x + a.y + a.z + a.w + b.x + b.y + b.z + b.w;
    #pragma unroll
    for (int off = 32; off; off >>= 1) sum += __shfl_down(sum, off);
    sum = __shfl(sum, 0);
    float mu = sum * (1.f / 512.f);
    float vs = 0.f;
    vs += (a.x - mu) * (a.x - mu); vs += (a.y - mu) * (a.y - mu);
    vs += (a.z - mu) * (a.z - mu); vs += (a.w - mu) * (a.w - mu);
    vs += (b.x - mu) * (b.x - mu); vs += (b.y - mu) * (b.y - mu);
    vs += (b.z - mu) * (b.z - mu); vs += (b.w - mu) * (b.w - mu);
    #pragma unroll
    for (int off = 32; off; off >>= 1) vs += __shfl_down(vs, off);
    if (lane == 0) {
        float var = vs * (1.f / 512.f);
        stats[row] = make_float2(mu, 1.0f / sqrtf(var + 1e-5f));
    }
}

// ---------------- kernel 2: projection GEMM -> transposed partials ----------------
__global__ __launch_bounds__(128) void proj_kernel(
    const float* __restrict__ H, const float2* __restrict__ stats,
    const float* __restrict__ lnw, const float* __restrict__ lnb,
    const float* __restrict__ Wp, float* __restrict__ Pt)
{
    __shared__ float Xt[64 * 32];        // [k][row] transposed, LN applied
    __shared__ float Ws[64 * CPAD];      // [k][c]
    int tid = threadIdx.x;
    int row0 = blockIdx.x * 32;
    int k0 = blockIdx.y * 64;

    {   // stage W chunk
        const float4* Wp4 = (const float4*)(Wp + k0 * CPAD);
        float4* Ws4 = (float4*)Ws;
        #pragma unroll
        for (int i = 0; i < 16; ++i) Ws4[tid + i * 128] = Wp4[tid + i * 128];
    }
    {   // stage X transposed with LayerNorm
        int r = tid >> 2, fq = tid & 3;
        int row = row0 + r;
        float2 st = stats[row];
        const float4* H4 = (const float4*)(H + row * D_MODEL + k0);
        const float4* w4 = (const float4*)(lnw + k0);
        const float4* b4 = (const float4*)(lnb + k0);
        #pragma unroll
        for (int it = 0; it < 4; ++it) {
            int q = fq + it * 4;
            float4 h = H4[q], wv = w4[q], bv = b4[q];
            Xt[(4 * q + 0) * 32 + r] = (h.x - st.x) * st.y * wv.x + bv.x;
            Xt[(4 * q + 1) * 32 + r] = (h.y - st.x) * st.y * wv.y + bv.y;
            Xt[(4 * q + 2) * 32 + r] = (h.z - st.x) * st.y * wv.z + bv.z;
            Xt[(4 * q + 3) * 32 + r] = (h.w - st.x) * st.y * wv.w + bv.w;
        }
    }
    __syncthreads();

    int q8 = tid & 15;
    int rg = tid >> 4;
    float acc[4][8];
    #pragma unroll
    for (int a = 0; a < 4; ++a)
        for (int u = 0; u < 8; ++u) acc[a][u] = 0.f;

    #pragma unroll 4
    for (int k = 0; k < 64; ++k) {
        float4 xa = *(float4*)&Xt[k * 32 + 4 * rg];
        float4 w0 = *(float4*)&Ws[k * CPAD + 8 * q8];
        float4 w1 = *(float4*)&Ws[k * CPAD + 8 * q8 + 4];
        float xv[4] = {xa.x, xa.y, xa.z, xa.w};
        float wv[8] = {w0.x, w0.y, w0.z, w0.w, w1.x, w1.y, w1.z, w1.w};
        #pragma unroll
        for (int a = 0; a < 4; ++a)
            #pragma unroll
            for (int u = 0; u < 8; ++u)
                acc[a][u] = fmaf(xv[a], wv[u], acc[a][u]);
    }

    if (q8 < 15) {
        #pragma unroll
        for (int u = 0; u < 8; ++u) {
            int c = 8 * q8 + u;
            if (c < NCOL) {
                float4 v = make_float4(acc[0][u], acc[1][u], acc[2][u], acc[3][u]);
                *(float4*)&Pt[((size_t)blockIdx.y * CPAD + c) * S_LEN + row0 + 4 * rg] = v;
            }
        }
    }
}

// ---------------- kernel 2.5: fold split-K partials + bias -> Pred[c][s] ----------------
__global__ __launch_bounds__(256) void reduce_kernel(const float* __restrict__ Pt,
                                                     const float* __restrict__ bias,
                                                     float* __restrict__ Pred)
{
    int c = blockIdx.y;
    int s4 = blockIdx.x * 256 + threadIdx.x;           // float4 index in [0,512)
    const float4* p4 = (const float4*)(Pt + (size_t)c * S_LEN) + s4;
    float b = bias[c];
    float4 acc = make_float4(b, b, b, b);
    #pragma unroll
    for (int kc = 0; kc < NKC; ++kc) {
        float4 v = p4[kc * (KCSTRIDE / 4)];
        acc.x += v.x; acc.y += v.y; acc.z += v.z; acc.w += v.w;
    }
    ((float4*)(Pred + (size_t)c * S_LEN))[s4] = acc;
}

// ---------------- kernel 3: triangular recurrence, 128src x 32dt wave-tiles ----------------
// Lane owns 2 ADJACENT sources (iA = i0+2*lane, iB = iA+1): one accumulator slide
// is register-local, so 1 LDS write+read serves TWO source-steps (R2's verified
// chain algebra), while the 32-dt tile keeps 544 tiles/imu = 7072 active waves
// (~6.9/SIMD) for latency hiding (R2's regression was the drop to 4.1/SIMD).
// Slot s = (i-i0)+t, s in [0,158]; LDS addr (s>>1)+(s&1)*96 -> per-instruction
// addresses are lane+const: stride-1, conflict-free, const folds into ds offset.
// Groups g = 4*sc + tc in [0,64): window j in [32g, 32g+159).
// grid.x = sum ceil((g/4+1)/4) = 160; grid (160, NIMU), 4 waves/block.
__global__ __launch_bounds__(256) void main_kernel(
    const float* __restrict__ Pred,
    const float* __restrict__ minp, float* __restrict__ out)
{
    __shared__ float buf[4 * 192];
    int tid = threadIdx.x;
    int lane = tid & 63, w = tid >> 6;
    int m = blockIdx.y;
    int bx = blockIdx.x;

    // decode bx -> (g, sub): group g has ceil((g/4+1)/4) = ((g>>2)+4)>>2 blocks
    int g = 0, base = 0;
    #pragma unroll 1
    for (;;) {
        int nb = ((g >> 2) + 4) >> 2;
        if (bx < base + nb) break;
        base += nb; ++g;
    }
    int sub = bx - base;
    int q = sub * 4 + w;               // tile index within group

    float* accW = buf + w * 192;
    accW[lane] = 0.f; accW[lane + 64] = 0.f; accW[lane + 128] = 0.f;
    __builtin_amdgcn_wave_barrier();

    if (q <= (g >> 2)) {
        int sc = q, tc = g - 4 * q;
        int i0 = sc * 128;
        float dtf = (float)(tc * 32);
        int iA = i0 + 2 * lane;

        // gather 9 fused params for sources iA, iA+1 (float2, coalesced, L2-hot)
        float pvA[9], pvB[9];
        #pragma unroll
        for (int p = 0; p < 9; ++p) {
            float2 v = *(const float2*)&Pred[(size_t)(p * 13 + m) * S_LEN + iA];
            pvA[p] = v.x; pvB[p] = v.y;
        }

        float reLA, imLA, zrLA, ziLA; osc_init(pvA[0], pvA[1], pvA[4], pvA[6], dtf, reLA, imLA, zrLA, ziLA);
        float reAA, imAA, zrAA, ziAA; osc_init(pvA[2], pvA[3], pvA[5], pvA[7], dtf, reAA, imAA, zrAA, ziAA);
        float reLB, imLB, zrLB, ziLB; osc_init(pvB[0], pvB[1], pvB[4], pvB[6], dtf, reLB, imLB, zrLB, ziLB);
        float reAB, imAB, zrAB, ziAB; osc_init(pvB[2], pvB[3], pvB[5], pvB[7], dtf, reAB, imAB, zrAB, ziAB);

        // a0 accumulates slot 2L+t, a1 accumulates slot 2L+1+t.
        // Slide: a0 <- a1 (register-local), a1 <- published a0 of lane L+1 (LDS).
        float a0 = 0.f, a1 = 0.f;
        float* wbase = accW + lane;
        #pragma unroll 8
        for (int t = 0; t < 32; ++t) {
            a0 += imLA + imAA;                 // source iA   -> slot 2L+t
            a1 += imLB + imAB;                 // source iA+1 -> slot 2L+1+t
            int c = (t >> 1) + (t & 1) * 96;   // addr of slot 2L+t minus lane (compile-time)
            wbase[c] = a0;                     // publish slot 2L+t
            __builtin_amdgcn_wave_barrier();   // pin write before cross-lane read
            float nxt = wbase[c + 1];          // slot 2L+2+t = lane L+1's publish (lane 63: boundary zeros)
            float tL = imLA * ziLA; float rL = fmaf(reLA, zrLA, -tL);
            imLA = fmaf(reLA, ziLA, imLA * zrLA); reLA = rL;
            float tA = imAA * ziAA; float rA = fmaf(reAA, zrAA, -tA);
            imAA = fmaf(reAA, ziAA, imAA * zrAA); reAA = rA;
            float tLB = imLB * ziLB; float rLB = fmaf(reLB, zrLB, -tLB);
            imLB = fmaf(reLB, ziLB, imLB * zrLB); reLB = rLB;
            float tAB = imAB * ziAB; float rAB = fmaf(reAB, zrAB, -tAB);
            imAB = fmaf(reAB, ziAB, imAB * zrAB); reAB = rAB;
            a0 = a1; a1 = nxt;
        }
        // after t=31: a0 = complete value of slot 2L+32 (even) -> addr lane+16
        __builtin_amdgcn_wave_barrier();
        wbase[16] = a0;
    }
    __syncthreads();

    // flush: window j in [32g, 32g+159); slot tid at addr (tid>>1)+(tid&1)*96
    if (tid < 159) {
        int j = g * 32 + tid;
        if (j < S_LEN) {
            int ad = (tid >> 1) + (tid & 1) * 96;
            float s = buf[ad] + buf[192 + ad] + buf[384 + ad] + buf[576 + ad];
            if (sub == 0 && tid < 32) {
                // exactly-once init: [32g, 32g+32) over g partitions [0, 2048)
                s += minp[0] + Pred[(size_t)(8 * 13 + m) * S_LEN + j];
            }
            atomicAdd(&out[m * S_LEN + j], s);
        }
    }
}

extern "C" void kernel_launch(void* const* d_in, const int* in_sizes, int n_in,
                              void* d_out, int out_size, void* d_ws, size_t ws_size,
                              hipStream_t stream)
{
    const float* H    = (const float*)d_in[0];
    const float* MINP = (const float*)d_in[1];
    const float* LNW  = (const float*)d_in[2];
    const float* LNB  = (const float*)d_in[3];
    const float* W    = (const float*)d_in[4];
    const float* B    = (const float*)d_in[5];
    float* out = (float*)d_out;

    const size_t PTSZ = (size_t)NKC * CPAD * S_LEN * sizeof(float);  // 8388608
    const size_t STSZ = S_LEN * sizeof(float2);                      // 16384
    const size_t WPSZ = (size_t)D_MODEL * CPAD * sizeof(float);      // 262144

    char* ws = (char*)d_ws;
    float*  Pt    = (float*)ws;
    float2* stats = (float2*)(ws + PTSZ);
    float*  Wp    = (float*)(ws + PTSZ + STSZ);
    float*  Pred  = (float*)(ws + PTSZ + STSZ + WPSZ);               // 117*2048*4 = 958464

    stats_kernel<<<512, 256, 0, stream>>>(H, stats, W, Wp, out);
    proj_kernel<<<dim3(64, 8), 128, 0, stream>>>(H, stats, LNW, LNB, Wp, Pt);
    reduce_kernel<<<dim3(2, NCOL), 256, 0, stream>>>(Pt, B, Pred);
    main_kernel<<<dim3(160, NIMU), 256, 0, stream>>>(Pred, MINP, out);
}

// Round 6
// 95.698 us; speedup vs baseline: 1.0234x; 1.0234x over previous
//
#include <hip/hip_runtime.h>
#include <math.h>

#define S_LEN 2048
#define D_MODEL 512
#define NIMU 13
#define NCOL 117                 // 13*9
#define CPAD 128                 // padded col stride
#define NKC 8                    // k-split chunks
// Pt[kc][c][s] = Pt[(kc*CPAD + c)*S_LEN + s]
#define KCSTRIDE ((size_t)CPAD * S_LEN)

static __device__ __forceinline__ float softplus_f(float x) {
    return (x > 20.f) ? x : log1pf(expf(x));
}

// osc transform: params -> per-step rotation z and state at dt0
static __device__ __forceinline__ void osc_init(float pk, float pd, float amp, float phi, float dtf,
                                                float& re, float& im, float& zr, float& zi)
{
    const float LOG2E = 1.4426950408889634f;
    const float INV2PI = 0.15915494309189535f;
    float d = sqrtf(pd * pd + 1e-5f);
    float kk = d * d * 0.25f + softplus_f(pk);
    float om = 0.5f * sqrtf(fmaxf(4.f * kk - d * d, 0.f));
    float y = -0.5f * d * LOG2E;       // log2 of decay per step
    float f = om * INV2PI;             // revolutions per step
    float ph = phi * INV2PI;
    float ez = __builtin_amdgcn_exp2f(y);
    zr = ez * __builtin_amdgcn_cosf(f);
    zi = ez * __builtin_amdgcn_sinf(f);
    float er = amp * __builtin_amdgcn_exp2f(dtf * y);
    float r = fmaf(dtf, f, ph); r -= floorf(r);
    re = er * __builtin_amdgcn_cosf(r);
    im = er * __builtin_amdgcn_sinf(r);
}

// ---------------- kernel 1: LN stats + W pad + out zero ----------------
__global__ __launch_bounds__(256) void stats_kernel(const float* __restrict__ H,
                                                    float2* __restrict__ stats,
                                                    const float* __restrict__ W,
                                                    float* __restrict__ Wp,
                                                    float* __restrict__ out) {
    if (blockIdx.x < 104) out[blockIdx.x * 256 + threadIdx.x] = 0.f;   // 104*256 = 26624 = 13*2048
    if (threadIdx.x < CPAD) {
        int c = threadIdx.x;
        Wp[blockIdx.x * CPAD + c] = (c < NCOL) ? W[blockIdx.x * NCOL + c] : 0.f;
    }
    int wave = threadIdx.x >> 6;
    int lane = threadIdx.x & 63;
    int row = blockIdx.x * 4 + wave;
    const float* hr = H + row * D_MODEL;
    float4 a = *(const float4*)&hr[lane * 4];
    float4 b = *(const float4*)&hr[256 + lane * 4];
    float sum = a.x + a.y + a.z + a.w + b.x + b.y + b.z + b.w;
    #pragma unroll
    for (int off = 32; off; off >>= 1) sum += __shfl_down(sum, off);
    sum = __shfl(sum, 0);
    float mu = sum * (1.f / 512.f);
    float vs = 0.f;
    vs += (a.x - mu) * (a.x - mu); vs += (a.y - mu) * (a.y - mu);
    vs += (a.z - mu) * (a.z - mu); vs += (a.w - mu) * (a.w - mu);
    vs += (b.x - mu) * (b.x - mu); vs += (b.y - mu) * (b.y - mu);
    vs += (b.z - mu) * (b.z - mu); vs += (b.w - mu) * (b.w - mu);
    #pragma unroll
    for (int off = 32; off; off >>= 1) vs += __shfl_down(vs, off);
    if (lane == 0) {
        float var = vs * (1.f / 512.f);
        stats[row] = make_float2(mu, 1.0f / sqrtf(var + 1e-5f));
    }
}

// ---------------- kernel 2: projection GEMM -> transposed partials ----------------
__global__ __launch_bounds__(128) void proj_kernel(
    const float* __restrict__ H, const float2* __restrict__ stats,
    const float* __restrict__ lnw, const float* __restrict__ lnb,
    const float* __restrict__ Wp, float* __restrict__ Pt)
{
    __shared__ float Xt[64 * 32];        // [k][row] transposed, LN applied
    __shared__ float Ws[64 * CPAD];      // [k][c]
    int tid = threadIdx.x;
    int row0 = blockIdx.x * 32;
    int k0 = blockIdx.y * 64;

    {   // stage W chunk
        const float4* Wp4 = (const float4*)(Wp + k0 * CPAD);
        float4* Ws4 = (float4*)Ws;
        #pragma unroll
        for (int i = 0; i < 16; ++i) Ws4[tid + i * 128] = Wp4[tid + i * 128];
    }
    {   // stage X transposed with LayerNorm
        int r = tid >> 2, fq = tid & 3;
        int row = row0 + r;
        float2 st = stats[row];
        const float4* H4 = (const float4*)(H + row * D_MODEL + k0);
        const float4* w4 = (const float4*)(lnw + k0);
        const float4* b4 = (const float4*)(lnb + k0);
        #pragma unroll
        for (int it = 0; it < 4; ++it) {
            int q = fq + it * 4;
            float4 h = H4[q], wv = w4[q], bv = b4[q];
            Xt[(4 * q + 0) * 32 + r] = (h.x - st.x) * st.y * wv.x + bv.x;
            Xt[(4 * q + 1) * 32 + r] = (h.y - st.x) * st.y * wv.y + bv.y;
            Xt[(4 * q + 2) * 32 + r] = (h.z - st.x) * st.y * wv.z + bv.z;
            Xt[(4 * q + 3) * 32 + r] = (h.w - st.x) * st.y * wv.w + bv.w;
        }
    }
    __syncthreads();

    int q8 = tid & 15;
    int rg = tid >> 4;
    float acc[4][8];
    #pragma unroll
    for (int a = 0; a < 4; ++a)
        for (int u = 0; u < 8; ++u) acc[a][u] = 0.f;

    #pragma unroll 4
    for (int k = 0; k < 64; ++k) {
        float4 xa = *(float4*)&Xt[k * 32 + 4 * rg];
        float4 w0 = *(float4*)&Ws[k * CPAD + 8 * q8];
        float4 w1 = *(float4*)&Ws[k * CPAD + 8 * q8 + 4];
        float xv[4] = {xa.x, xa.y, xa.z, xa.w};
        float wv[8] = {w0.x, w0.y, w0.z, w0.w, w1.x, w1.y, w1.z, w1.w};
        #pragma unroll
        for (int a = 0; a < 4; ++a)
            #pragma unroll
            for (int u = 0; u < 8; ++u)
                acc[a][u] = fmaf(xv[a], wv[u], acc[a][u]);
    }

    if (q8 < 15) {
        #pragma unroll
        for (int u = 0; u < 8; ++u) {
            int c = 8 * q8 + u;
            if (c < NCOL) {
                float4 v = make_float4(acc[0][u], acc[1][u], acc[2][u], acc[3][u]);
                *(float4*)&Pt[((size_t)blockIdx.y * CPAD + c) * S_LEN + row0 + 4 * rg] = v;
            }
        }
    }
}

// ---------------- kernel 2.5: fold split-K partials + bias -> Pred[c][s] ----------------
__global__ __launch_bounds__(256) void reduce_kernel(const float* __restrict__ Pt,
                                                     const float* __restrict__ bias,
                                                     float* __restrict__ Pred)
{
    int c = blockIdx.y;
    int s4 = blockIdx.x * 256 + threadIdx.x;           // float4 index in [0,512)
    const float4* p4 = (const float4*)(Pt + (size_t)c * S_LEN) + s4;
    float b = bias[c];
    float4 acc = make_float4(b, b, b, b);
    #pragma unroll
    for (int kc = 0; kc < NKC; ++kc) {
        float4 v = p4[kc * (KCSTRIDE / 4)];
        acc.x += v.x; acc.y += v.y; acc.z += v.z; acc.w += v.w;
    }
    ((float4*)(Pred + (size_t)c * S_LEN))[s4] = acc;
}

// ---------------- kernel 3: triangular recurrence (R1 tiling, shuffle-chain loop) ----------
// 64 src x 64 dt wave-tiles, grid (144, NIMU), 4 waves/block (~6.9 active waves/SIMD).
// Accumulator chain: slot s = lane+t enters at lane 63 as 0, flows DOWN one lane
// per step via __shfl_down (replaces per-iter ds_write+barrier+ds_read+stall),
// completes at lane 0 at step t=s. Lane 0 banks completed slot t with a
// fire-and-forget ds_write (lanes 1-63 write a dummy stride-1 region: 2 lanes/bank
// aliasing = free). Partial slots 64..127 are flushed from registers at tile end
// and covered by tile (sc,tc+1) via the atomicAdd merge (R1's verified scheme).
// Per-wave LDS section: [0,128) real slots, [128,192) dummy.
__global__ __launch_bounds__(256) void main_kernel(
    const float* __restrict__ Pred,
    const float* __restrict__ minp, float* __restrict__ out)
{
    __shared__ float buf[4 * 192];
    int tid = threadIdx.x;
    int lane = tid & 63, w = tid >> 6;
    int m = blockIdx.y;
    int bx = blockIdx.x;

    // decode bx -> (g, sub): group g has ceil((g+1)/4) = (g+4)>>2 blocks
    int g = 0, base = 0;
    #pragma unroll 1
    for (;;) {
        int nb = (g + 4) >> 2;
        if (bx < base + nb) break;
        base += nb; ++g;
    }
    int sub = bx - base;
    int q = sub * 4 + w;               // tile index within group

    float* accW = buf + w * 192;
    accW[lane] = 0.f; accW[lane + 64] = 0.f;   // zeros persist for inactive waves
    __builtin_amdgcn_wave_barrier();

    if (q <= g) {
        int sc = q, tc = g - q;
        int i0 = sc * 64;
        float dtf = (float)(tc * 64);

        // gather 9 fused params for source i0+lane (coalesced, Pred is 1 MB -> L2-hot)
        float pv[9];
        #pragma unroll
        for (int p = 0; p < 9; ++p)
            pv[p] = Pred[(size_t)(p * 13 + m) * S_LEN + i0 + lane];

        float reL, imL, zrL, ziL; osc_init(pv[0], pv[1], pv[4], pv[6], dtf, reL, imL, zrL, ziL);
        float reA, imA, zrA, ziA; osc_init(pv[2], pv[3], pv[5], pv[7], dtf, reA, imA, zrA, ziA);

        float a = 0.f;                 // lane L holds the accumulator of slot L+t at step t
        bool first = (lane == 0);
        bool last  = (lane == 63);
        #pragma unroll 8
        for (int t = 0; t < 64; ++t) {
            a += imL + imA;                        // contribute to slot lane+t
            int ad = first ? t : (128 + lane);     // lane0: bank slot t; others: dummy (free)
            accW[ad] = a;                          // fire-and-forget, off critical path
            float nx = __shfl_down(a, 1);          // slide chain down one lane
            nx = last ? 0.f : nx;                  // inject fresh slot at lane 63
            float tL = imL * ziL; float rL = fmaf(reL, zrL, -tL);
            imL = fmaf(reL, ziL, imL * zrL); reL = rL;
            float tA = imA * ziA; float rA = fmaf(reA, zrA, -tA);
            imA = fmaf(reA, ziA, imA * zrA); reA = rA;
            a = nx;
        }
        accW[64 + lane] = a;                       // slots 64..126 partials; lane63 -> slot127 = 0
    }
    __syncthreads();

    // flush: window j in [64g, 64g+128); first half init'd exactly once (sub==0)
    if (tid < 128) {
        int j = g * 64 + tid;
        if (j < S_LEN) {
            float s = buf[tid] + buf[192 + tid] + buf[384 + tid] + buf[576 + tid];
            if (sub == 0 && tid < 64) {
                s += minp[0] + Pred[(size_t)(8 * 13 + m) * S_LEN + j];
            }
            atomicAdd(&out[m * S_LEN + j], s);
        }
    }
}

extern "C" void kernel_launch(void* const* d_in, const int* in_sizes, int n_in,
                              void* d_out, int out_size, void* d_ws, size_t ws_size,
                              hipStream_t stream)
{
    const float* H    = (const float*)d_in[0];
    const float* MINP = (const float*)d_in[1];
    const float* LNW  = (const float*)d_in[2];
    const float* LNB  = (const float*)d_in[3];
    const float* W    = (const float*)d_in[4];
    const float* B    = (const float*)d_in[5];
    float* out = (float*)d_out;

    const size_t PTSZ = (size_t)NKC * CPAD * S_LEN * sizeof(float);  // 8388608
    const size_t STSZ = S_LEN * sizeof(float2);                      // 16384
    const size_t WPSZ = (size_t)D_MODEL * CPAD * sizeof(float);      // 262144

    char* ws = (char*)d_ws;
    float*  Pt    = (float*)ws;
    float2* stats = (float2*)(ws + PTSZ);
    float*  Wp    = (float*)(ws + PTSZ + STSZ);
    float*  Pred  = (float*)(ws + PTSZ + STSZ + WPSZ);               // 117*2048*4 = 958464

    stats_kernel<<<512, 256, 0, stream>>>(H, stats, W, Wp, out);
    proj_kernel<<<dim3(64, 8), 128, 0, stream>>>(H, stats, LNW, LNB, Wp, Pt);
    reduce_kernel<<<dim3(2, NCOL), 256, 0, stream>>>(Pt, B, Pred);
    main_kernel<<<dim3(144, NIMU), 256, 0, stream>>>(Pred, MINP, out);
}

// Round 7
// 91.877 us; speedup vs baseline: 1.0660x; 1.0416x over previous
//
#include <hip/hip_runtime.h>
#include <math.h>

#define S_LEN 2048
#define D_MODEL 512
#define NIMU 13
#define NCOL 117                 // 13*9
#define CPAD 128                 // padded col stride
#define NKC 8                    // k-split chunks
// Pt[kc][c][s] = Pt[(kc*CPAD + c)*S_LEN + s]
#define KCSTRIDE ((size_t)CPAD * S_LEN)

static __device__ __forceinline__ float softplus_f(float x) {
    return (x > 20.f) ? x : log1pf(expf(x));
}

// osc transform: params -> per-step rotation z and state at dt0
static __device__ __forceinline__ void osc_init(float pk, float pd, float amp, float phi, float dtf,
                                                float& re, float& im, float& zr, float& zi)
{
    const float LOG2E = 1.4426950408889634f;
    const float INV2PI = 0.15915494309189535f;
    float d = sqrtf(pd * pd + 1e-5f);
    float kk = d * d * 0.25f + softplus_f(pk);
    float om = 0.5f * sqrtf(fmaxf(4.f * kk - d * d, 0.f));
    float y = -0.5f * d * LOG2E;       // log2 of decay per step
    float f = om * INV2PI;             // revolutions per step
    float ph = phi * INV2PI;
    float ez = __builtin_amdgcn_exp2f(y);
    zr = ez * __builtin_amdgcn_cosf(f);
    zi = ez * __builtin_amdgcn_sinf(f);
    float er = amp * __builtin_amdgcn_exp2f(dtf * y);
    float r = fmaf(dtf, f, ph); r -= floorf(r);
    re = er * __builtin_amdgcn_cosf(r);
    im = er * __builtin_amdgcn_sinf(r);
}

// ---------------- kernel 1: LN stats + W pad + out zero ----------------
__global__ __launch_bounds__(256) void stats_kernel(const float* __restrict__ H,
                                                    float2* __restrict__ stats,
                                                    const float* __restrict__ W,
                                                    float* __restrict__ Wp,
                                                    float* __restrict__ out) {
    if (blockIdx.x < 104) out[blockIdx.x * 256 + threadIdx.x] = 0.f;   // 104*256 = 26624 = 13*2048
    if (threadIdx.x < CPAD) {
        int c = threadIdx.x;
        Wp[blockIdx.x * CPAD + c] = (c < NCOL) ? W[blockIdx.x * NCOL + c] : 0.f;
    }
    int wave = threadIdx.x >> 6;
    int lane = threadIdx.x & 63;
    int row = blockIdx.x * 4 + wave;
    const float* hr = H + row * D_MODEL;
    float4 a = *(const float4*)&hr[lane * 4];
    float4 b = *(const float4*)&hr[256 + lane * 4];
    float sum = a.x + a.y + a.z + a.w + b.x + b.y + b.z + b.w;
    #pragma unroll
    for (int off = 32; off; off >>= 1) sum += __shfl_down(sum, off);
    sum = __shfl(sum, 0);
    float mu = sum * (1.f / 512.f);
    float vs = 0.f;
    vs += (a.x - mu) * (a.x - mu); vs += (a.y - mu) * (a.y - mu);
    vs += (a.z - mu) * (a.z - mu); vs += (a.w - mu) * (a.w - mu);
    vs += (b.x - mu) * (b.x - mu); vs += (b.y - mu) * (b.y - mu);
    vs += (b.z - mu) * (b.z - mu); vs += (b.w - mu) * (b.w - mu);
    #pragma unroll
    for (int off = 32; off; off >>= 1) vs += __shfl_down(vs, off);
    if (lane == 0) {
        float var = vs * (1.f / 512.f);
        stats[row] = make_float2(mu, 1.0f / sqrtf(var + 1e-5f));
    }
}

// ---------------- kernel 2: projection GEMM -> transposed partials ----------------
__global__ __launch_bounds__(128) void proj_kernel(
    const float* __restrict__ H, const float2* __restrict__ stats,
    const float* __restrict__ lnw, const float* __restrict__ lnb,
    const float* __restrict__ Wp, float* __restrict__ Pt)
{
    __shared__ float Xt[64 * 32];        // [k][row] transposed, LN applied
    __shared__ float Ws[64 * CPAD];      // [k][c]
    int tid = threadIdx.x;
    int row0 = blockIdx.x * 32;
    int k0 = blockIdx.y * 64;

    {   // stage W chunk
        const float4* Wp4 = (const float4*)(Wp + k0 * CPAD);
        float4* Ws4 = (float4*)Ws;
        #pragma unroll
        for (int i = 0; i < 16; ++i) Ws4[tid + i * 128] = Wp4[tid + i * 128];
    }
    {   // stage X transposed with LayerNorm
        int r = tid >> 2, fq = tid & 3;
        int row = row0 + r;
        float2 st = stats[row];
        const float4* H4 = (const float4*)(H + row * D_MODEL + k0);
        const float4* w4 = (const float4*)(lnw + k0);
        const float4* b4 = (const float4*)(lnb + k0);
        #pragma unroll
        for (int it = 0; it < 4; ++it) {
            int q = fq + it * 4;
            float4 h = H4[q], wv = w4[q], bv = b4[q];
            Xt[(4 * q + 0) * 32 + r] = (h.x - st.x) * st.y * wv.x + bv.x;
            Xt[(4 * q + 1) * 32 + r] = (h.y - st.x) * st.y * wv.y + bv.y;
            Xt[(4 * q + 2) * 32 + r] = (h.z - st.x) * st.y * wv.z + bv.z;
            Xt[(4 * q + 3) * 32 + r] = (h.w - st.x) * st.y * wv.w + bv.w;
        }
    }
    __syncthreads();

    int q8 = tid & 15;
    int rg = tid >> 4;
    float acc[4][8];
    #pragma unroll
    for (int a = 0; a < 4; ++a)
        for (int u = 0; u < 8; ++u) acc[a][u] = 0.f;

    #pragma unroll 4
    for (int k = 0; k < 64; ++k) {
        float4 xa = *(float4*)&Xt[k * 32 + 4 * rg];
        float4 w0 = *(float4*)&Ws[k * CPAD + 8 * q8];
        float4 w1 = *(float4*)&Ws[k * CPAD + 8 * q8 + 4];
        float xv[4] = {xa.x, xa.y, xa.z, xa.w};
        float wv[8] = {w0.x, w0.y, w0.z, w0.w, w1.x, w1.y, w1.z, w1.w};
        #pragma unroll
        for (int a = 0; a < 4; ++a)
            #pragma unroll
            for (int u = 0; u < 8; ++u)
                acc[a][u] = fmaf(xv[a], wv[u], acc[a][u]);
    }

    if (q8 < 15) {
        #pragma unroll
        for (int u = 0; u < 8; ++u) {
            int c = 8 * q8 + u;
            if (c < NCOL) {
                float4 v = make_float4(acc[0][u], acc[1][u], acc[2][u], acc[3][u]);
                *(float4*)&Pt[((size_t)blockIdx.y * CPAD + c) * S_LEN + row0 + 4 * rg] = v;
            }
        }
    }
}

// ---------------- kernel 2.5: fold split-K partials + bias -> Pred[c][s] ----------------
__global__ __launch_bounds__(256) void reduce_kernel(const float* __restrict__ Pt,
                                                     const float* __restrict__ bias,
                                                     float* __restrict__ Pred)
{
    int c = blockIdx.y;
    int s4 = blockIdx.x * 256 + threadIdx.x;           // float4 index in [0,512)
    const float4* p4 = (const float4*)(Pt + (size_t)c * S_LEN) + s4;
    float b = bias[c];
    float4 acc = make_float4(b, b, b, b);
    #pragma unroll
    for (int kc = 0; kc < NKC; ++kc) {
        float4 v = p4[kc * (KCSTRIDE / 4)];
        acc.x += v.x; acc.y += v.y; acc.z += v.z; acc.w += v.w;
    }
    ((float4*)(Pred + (size_t)c * S_LEN))[s4] = acc;
}

// ---------------- kernel 3: triangular recurrence, 64x64 wave-tiles (best: R1) ----------
// grid (144, NIMU); block 256 = 4 waves. Group g in [0,32): g+1 tiles, window
// j in [64g, 64g+128). Tile q=(sc,tc): lane owns source i0+lane at dt = 64*tc + t.
// 1872 blocks * 4 waves = 7488 waves ~= 6.9 active/SIMD for latency hiding.
// Inner loop: software-pipelined sliding-window LDS RMW (prefetch slot t+1 under
// the rotation VALU). Beat 2-src LDS (R2), 2-src small-tile (R4), shuffle-chain (R6).
__global__ __launch_bounds__(256) void main_kernel(
    const float* __restrict__ Pred,
    const float* __restrict__ minp, float* __restrict__ out)
{
    __shared__ float buf[4 * 128];
    int tid = threadIdx.x;
    int lane = tid & 63, w = tid >> 6;
    int m = blockIdx.y;
    int bx = blockIdx.x;

    // decode bx -> (g, sub): group g has ceil((g+1)/4) = (g+4)>>2 blocks
    int g = 0, base = 0;
    #pragma unroll 1
    for (;;) {
        int nb = (g + 4) >> 2;
        if (bx < base + nb) break;
        base += nb; ++g;
    }
    int sub = bx - base;
    int q = sub * 4 + w;               // tile index within group

    float* accW = buf + w * 128;
    accW[lane] = 0.f; accW[lane + 64] = 0.f;
    __builtin_amdgcn_wave_barrier();

    if (q <= g) {
        int sc = q, tc = g - q;
        int i0 = sc * 64;
        float dtf = (float)(tc * 64);

        // gather 9 fused params for source i0+lane (coalesced, Pred is 1 MB -> L2-hot)
        float pv[9];
        #pragma unroll
        for (int p = 0; p < 9; ++p)
            pv[p] = Pred[(size_t)(p * 13 + m) * S_LEN + i0 + lane];

        float reL, imL, zrL, ziL; osc_init(pv[0], pv[1], pv[4], pv[6], dtf, reL, imL, zrL, ziL);
        float reA, imA, zrA, ziA; osc_init(pv[2], pv[3], pv[5], pv[7], dtf, reA, imA, zrA, ziA);

        // software-pipelined sliding-window RMW:
        //   carry slot value in register `a`; after writing slot lane+t, prefetch slot
        //   lane+t+1 (just written by lane+1 in the same in-order LDS instruction) and
        //   hide its latency under the 8 rotation VALU ops.
        float a = 0.f;                 // slot `lane` is freshly zeroed, first writer is us at t=0
        #pragma unroll 8
        for (int t = 0; t < 64; ++t) {
            a += imL + imA;
            accW[lane + t] = a;
            __builtin_amdgcn_wave_barrier();   // pin write(t) before read(t+1)
            float nxt = accW[lane + t + 1];    // max index 63+64 = 127, in bounds
            float tL = imL * ziL; float rL = fmaf(reL, zrL, -tL);
            imL = fmaf(reL, ziL, imL * zrL); reL = rL;
            float tA = imA * ziA; float rA = fmaf(reA, zrA, -tA);
            imA = fmaf(reA, ziA, imA * zrA); reA = rA;
            a = nxt;
        }
    }
    __syncthreads();

    // flush: window j in [64g, 64g+128); first half init'd exactly once (sub==0)
    if (tid < 128) {
        int j = g * 64 + tid;
        if (j < S_LEN) {
            float s = buf[tid] + buf[128 + tid] + buf[256 + tid] + buf[384 + tid];
            if (sub == 0 && tid < 64) {
                s += minp[0] + Pred[(size_t)(8 * 13 + m) * S_LEN + j];
            }
            atomicAdd(&out[m * S_LEN + j], s);
        }
    }
}

extern "C" void kernel_launch(void* const* d_in, const int* in_sizes, int n_in,
                              void* d_out, int out_size, void* d_ws, size_t ws_size,
                              hipStream_t stream)
{
    const float* H    = (const float*)d_in[0];
    const float* MINP = (const float*)d_in[1];
    const float* LNW  = (const float*)d_in[2];
    const float* LNB  = (const float*)d_in[3];
    const float* W    = (const float*)d_in[4];
    const float* B    = (const float*)d_in[5];
    float* out = (float*)d_out;

    const size_t PTSZ = (size_t)NKC * CPAD * S_LEN * sizeof(float);  // 8388608
    const size_t STSZ = S_LEN * sizeof(float2);                      // 16384
    const size_t WPSZ = (size_t)D_MODEL * CPAD * sizeof(float);      // 262144

    char* ws = (char*)d_ws;
    float*  Pt    = (float*)ws;
    float2* stats = (float2*)(ws + PTSZ);
    float*  Wp    = (float*)(ws + PTSZ + STSZ);
    float*  Pred  = (float*)(ws + PTSZ + STSZ + WPSZ);               // 117*2048*4 = 958464

    stats_kernel<<<512, 256, 0, stream>>>(H, stats, W, Wp, out);
    proj_kernel<<<dim3(64, 8), 128, 0, stream>>>(H, stats, LNW, LNB, Wp, Pt);
    reduce_kernel<<<dim3(2, NCOL), 256, 0, stream>>>(Pt, B, Pred);
    main_kernel<<<dim3(144, NIMU), 256, 0, stream>>>(Pred, MINP, out);
}